// Round 9
// baseline (1943.415 us; speedup 1.0000x reference)
//
#include <hip/hip_runtime.h>
#include <math.h>

#define EPSN 1e-12f

typedef __attribute__((ext_vector_type(8))) short short8;
typedef __attribute__((ext_vector_type(4))) float f32x4;
typedef __attribute__((ext_vector_type(16))) float f32x16;

// ---------------------------------------------------------------------------
// helpers
// ---------------------------------------------------------------------------
__device__ __forceinline__ void split_hi_lo(float x, unsigned short& h, unsigned short& l)
{
    unsigned int xb = __float_as_uint(x);
    h = (unsigned short)(xb >> 16);
    float r = x - __uint_as_float(xb & 0xffff0000u);
    l = (unsigned short)(__float_as_uint(r) >> 16);
}

__device__ __forceinline__ unsigned short f2bf_rne(float x)
{
    unsigned int u = __float_as_uint(x);
    unsigned int r = u + 0x7fffu + ((u >> 16) & 1u);
    return (unsigned short)(r >> 16);
}

// async global->LDS, 16B per lane; LDS dest = wave-uniform base + lane*16
__device__ __forceinline__ void gload16(const void* g, void* l)
{
    __builtin_amdgcn_global_load_lds(
        (const __attribute__((address_space(1))) void*)g,
        (__attribute__((address_space(3))) void*)l, 16, 0, 0);
}

// ---- BK=64 plane helpers (gemm_w fallback) ----
__device__ __forceinline__ short8 read_frag(const unsigned char* plane, int row, int chunk)
{
    int byte = row * 128 + ((chunk ^ (row & 7)) << 4);
    return *reinterpret_cast<const short8*>(plane + byte);
}

__device__ __forceinline__ void stage_split(const float* __restrict__ src, int K, int k0,
                                            unsigned char* hi_plane, unsigned char* lo_plane,
                                            int tid)
{
#pragma unroll
    for (int q = 0; q < 8; ++q) {
        int idx = tid + q * 256;
        int row = idx >> 4;
        int f4  = idx & 15;
        float4 v = *reinterpret_cast<const float4*>(&src[(size_t)row * K + k0 + f4 * 4]);
        unsigned short h[4], l[4];
        split_hi_lo(v.x, h[0], l[0]);
        split_hi_lo(v.y, h[1], l[1]);
        split_hi_lo(v.z, h[2], l[2]);
        split_hi_lo(v.w, h[3], l[3]);
        int byte = row * 128 + (((f4 >> 1) ^ (row & 7)) << 4) + (f4 & 1) * 8;
        *reinterpret_cast<ushort4*>(hi_plane + byte) = make_ushort4(h[0], h[1], h[2], h[3]);
        *reinterpret_cast<ushort4*>(lo_plane + byte) = make_ushort4(l[0], l[1], l[2], l[3]);
    }
}

// ---- BK=32 64B-row plane helpers (gemm_ps + fused) ----
// rows 64B (32 bf16), 4 chunks; swizzle chunk^((row>>1)&3) -> ~2-way (free).
__device__ __forceinline__ short8 read_frag32(const unsigned char* plane, int row, int ch)
{
    int byte = row * 64 + ((ch ^ ((row >> 1) & 3)) << 4);
    return *reinterpret_cast<const short8*>(plane + byte);
}

// ---------------------------------------------------------------------------
// tiny prep kernels
// ---------------------------------------------------------------------------
__global__ __launch_bounds__(256)
void split_rows(const float* __restrict__ src, unsigned short* __restrict__ dst)
{
    const int row = blockIdx.x, tid = threadIdx.x;
    float4 v = reinterpret_cast<const float4*>(src + (size_t)row * 1024)[tid];
    unsigned short h[4], l[4];
    split_hi_lo(v.x, h[0], l[0]); split_hi_lo(v.y, h[1], l[1]);
    split_hi_lo(v.z, h[2], l[2]); split_hi_lo(v.w, h[3], l[3]);
    unsigned short* R = dst + (size_t)row * 2048;
    *reinterpret_cast<ushort4*>(R + tid * 4)        = make_ushort4(h[0], h[1], h[2], h[3]);
    *reinterpret_cast<ushort4*>(R + 1024 + tid * 4) = make_ushort4(l[0], l[1], l[2], l[3]);
}

__global__ __launch_bounds__(256)
void l2norm_split(float* __restrict__ X)
{
    const int row = blockIdx.x, tid = threadIdx.x;
    float* Xr = X + (size_t)row * 1024;
    float4 v = reinterpret_cast<float4*>(Xr)[tid];
    float s = v.x * v.x + v.y * v.y + v.z * v.z + v.w * v.w;
#pragma unroll
    for (int off = 32; off > 0; off >>= 1) s += __shfl_down(s, off);
    __shared__ float red[4];
    __shared__ float scale_sh;
    if ((tid & 63) == 0) red[tid >> 6] = s;
    __syncthreads();
    if (tid == 0) {
        float n = sqrtf(red[0] + red[1] + red[2] + red[3]);
        scale_sh = 1.f / fmaxf(n, EPSN);
    }
    __syncthreads();
    const float sc = scale_sh;
    v.x *= sc; v.y *= sc; v.z *= sc; v.w *= sc;
    unsigned short h[4], l[4];
    split_hi_lo(v.x, h[0], l[0]); split_hi_lo(v.y, h[1], l[1]);
    split_hi_lo(v.z, h[2], l[2]); split_hi_lo(v.w, h[3], l[3]);
    unsigned short* R = reinterpret_cast<unsigned short*>(Xr);
    *reinterpret_cast<ushort4*>(R + tid * 4)        = make_ushort4(h[0], h[1], h[2], h[3]);
    *reinterpret_cast<ushort4*>(R + 1024 + tid * 4) = make_ushort4(l[0], l[1], l[2], l[3]);
}

__global__ __launch_bounds__(256)
void transpose_exR(const float* __restrict__ exR, unsigned short* __restrict__ exT, int N)
{
    __shared__ unsigned short sm[64][256];
    const int tid = threadIdx.x;
    const int n0 = blockIdx.x * 256;
    const float4* src = reinterpret_cast<const float4*>(exR + (size_t)(n0 + tid) * 64);
#pragma unroll
    for (int q = 0; q < 16; ++q) {
        float4 v = src[q];
        sm[q * 4 + 0][tid] = f2bf_rne(v.x);
        sm[q * 4 + 1][tid] = f2bf_rne(v.y);
        sm[q * 4 + 2][tid] = f2bf_rne(v.z);
        sm[q * 4 + 3][tid] = f2bf_rne(v.w);
    }
    __syncthreads();
#pragma unroll
    for (int j = 0; j < 32; ++j) {
        int idx = tid + j * 256;
        int c = idx >> 7, nl2 = idx & 127;
        *reinterpret_cast<ushort2*>(exT + (size_t)c * N + n0 + nl2 * 2) =
            *reinterpret_cast<const ushort2*>(&sm[c][nl2 * 2]);
    }
}

// ---------------------------------------------------------------------------
// Pre-split projection GEMM (unchanged from round 8: BK=32 dbuf, 16x16 MFMA)
// ---------------------------------------------------------------------------
__device__ __forceinline__ void make_off32(int wave, int lane, int off32[2])
{
#pragma unroll
    for (int i = 0; i < 2; ++i) {
        int t   = (wave * 2 + i) * 64 + lane;
        int row = t >> 2;
        int cl  = t & 3;
        int cg  = cl ^ ((row >> 1) & 3);
        off32[i] = row * 4096 + cg * 16;
    }
}

__device__ __forceinline__ void stage32(const char* Ab, const char* Bb, int k2,
                                        unsigned char* buf, const int off32[2], int wave)
{
#pragma unroll
    for (int i = 0; i < 2; ++i) {
        unsigned char* d = buf + (wave * 2 + i) * 1024;
        gload16(Ab + off32[i] + k2,        d);             // A_hi
        gload16(Ab + off32[i] + 2048 + k2, d + 8192);      // A_lo
        gload16(Bb + off32[i] + k2,        d + 16384);     // B_hi
        gload16(Bb + off32[i] + 2048 + k2, d + 24576);     // B_lo
    }
}

__device__ __forceinline__ void compute32(const unsigned char* buf, int lane, int wr, int wc,
                                          f32x4 acc[4][4])
{
    const int ch = lane >> 4;
    short8 bh[4], bl[4];
#pragma unroll
    for (int fn = 0; fn < 4; ++fn) {
        int rb = wc * 64 + fn * 16 + (lane & 15);
        bh[fn] = read_frag32(buf + 16384, rb, ch);
        bl[fn] = read_frag32(buf + 24576, rb, ch);
    }
#pragma unroll
    for (int fm = 0; fm < 4; ++fm) {
        int ra = wr * 64 + fm * 16 + (lane & 15);
        short8 ah = read_frag32(buf,        ra, ch);
        short8 al = read_frag32(buf + 8192, ra, ch);
#pragma unroll
        for (int fn = 0; fn < 4; ++fn) {
            acc[fm][fn] = __builtin_amdgcn_mfma_f32_16x16x32_bf16(ah, bh[fn], acc[fm][fn], 0, 0, 0);
            acc[fm][fn] = __builtin_amdgcn_mfma_f32_16x16x32_bf16(ah, bl[fn], acc[fm][fn], 0, 0, 0);
            acc[fm][fn] = __builtin_amdgcn_mfma_f32_16x16x32_bf16(al, bh[fn], acc[fm][fn], 0, 0, 0);
        }
    }
}

__global__ __launch_bounds__(256, 2)
void gemm_ps(const unsigned short* __restrict__ spA, const unsigned short* __restrict__ spW,
             float* __restrict__ C, int Nn, int K)
{
    __shared__ __align__(16) unsigned char S[65536];

    const int tid  = threadIdx.x;
    const int lane = tid & 63;
    const int wave = tid >> 6;
    const int wr = wave >> 1, wc = wave & 1;
    const int brow = blockIdx.y * 128;
    const int bcol = blockIdx.x * 128;
    const char* Ab = (const char*)spA + (size_t)brow * 4096;
    const char* Wb = (const char*)spW + (size_t)bcol * 4096;

    int off32[2];
    make_off32(wave, lane, off32);

    f32x4 acc[4][4] = {};
    const int nk = K / 32;

    stage32(Ab, Wb, 0, S, off32, wave);
    __syncthreads();
    int cur = 0;
    for (int k = 0; k < nk; ++k) {
        if (k + 1 < nk)
            stage32(Ab, Wb, (k + 1) * 64, S + (cur ^ 1) * 32768, off32, wave);
        compute32(S + cur * 32768, lane, wr, wc, acc);
        __syncthreads();
        cur ^= 1;
    }

#pragma unroll
    for (int fm = 0; fm < 4; ++fm)
#pragma unroll
        for (int fn = 0; fn < 4; ++fn)
#pragma unroll
            for (int reg = 0; reg < 4; ++reg) {
                int row = brow + wr * 64 + fm * 16 + (lane >> 4) * 4 + reg;
                int col = bcol + wc * 64 + fn * 16 + (lane & 15);
                C[(size_t)row * Nn + col] = acc[fm][fn][reg];
            }
}

// ---------------------------------------------------------------------------
// Fallback projection GEMM (BK=64 single-buffer, reg-staged A split)
// ---------------------------------------------------------------------------
__global__ __launch_bounds__(256, 2)
void gemm_w(const float* __restrict__ A, const unsigned short* __restrict__ spW,
            float* __restrict__ C, int Nn, int K)
{
    __shared__ __align__(16) unsigned char smem[65536];
    unsigned char* sA_hi = smem;
    unsigned char* sA_lo = smem + 16384;
    unsigned char* sB_hi = smem + 32768;
    unsigned char* sB_lo = smem + 49152;

    const int tid  = threadIdx.x;
    const int lane = tid & 63;
    const int wave = tid >> 6;
    const int wr = wave >> 1, wc = wave & 1;
    const int brow = blockIdx.y * 128;
    const int bcol = blockIdx.x * 128;
    const float* Abase = A + (size_t)brow * K;
    const char*  Wbase = (const char*)spW + (size_t)bcol * 4096;

    int offW[4];
#pragma unroll
    for (int i = 0; i < 4; ++i) {
        int t = (wave * 4 + i) * 64 + lane;
        int r = t >> 3, c = (t & 7) ^ (r & 7);
        offW[i] = r * 4096 + c * 16;
    }

    f32x4 acc[4][4] = {};

    for (int k0 = 0; k0 < K; k0 += 64) {
        const int k2 = k0 * 2;
#pragma unroll
        for (int i = 0; i < 4; ++i) {
            gload16(Wbase + offW[i] + k2,        sB_hi + (wave * 4 + i) * 1024);
            gload16(Wbase + offW[i] + 2048 + k2, sB_lo + (wave * 4 + i) * 1024);
        }
        stage_split(Abase, K, k0, sA_hi, sA_lo, tid);
        __syncthreads();
#pragma unroll
        for (int kk = 0; kk < 2; ++kk) {
            const int ch = kk * 4 + (lane >> 4);
            short8 bh[4], bl[4];
#pragma unroll
            for (int fn = 0; fn < 4; ++fn) {
                int rb = wc * 64 + fn * 16 + (lane & 15);
                bh[fn] = read_frag(sB_hi, rb, ch);
                bl[fn] = read_frag(sB_lo, rb, ch);
            }
#pragma unroll
            for (int fm = 0; fm < 4; ++fm) {
                int ra = wr * 64 + fm * 16 + (lane & 15);
                short8 ah = read_frag(sA_hi, ra, ch);
                short8 al = read_frag(sA_lo, ra, ch);
#pragma unroll
                for (int fn = 0; fn < 4; ++fn) {
                    acc[fm][fn] = __builtin_amdgcn_mfma_f32_16x16x32_bf16(ah, bh[fn], acc[fm][fn], 0, 0, 0);
                    acc[fm][fn] = __builtin_amdgcn_mfma_f32_16x16x32_bf16(ah, bl[fn], acc[fm][fn], 0, 0, 0);
                    acc[fm][fn] = __builtin_amdgcn_mfma_f32_16x16x32_bf16(al, bh[fn], acc[fm][fn], 0, 0, 0);
                }
            }
        }
        __syncthreads();
    }

#pragma unroll
    for (int fm = 0; fm < 4; ++fm)
#pragma unroll
        for (int fn = 0; fn < 4; ++fn)
#pragma unroll
            for (int reg = 0; reg < 4; ++reg) {
                int row = brow + wr * 64 + fm * 16 + (lane >> 4) * 4 + reg;
                int col = bcol + wc * 64 + fn * 16 + (lane & 15);
                C[(size_t)row * Nn + col] = acc[fm][fn][reg];
            }
}

// ---------------------------------------------------------------------------
// Fused kernel v3: block 128x256, wave tile 64x128, 32x32x16 MFMA, BK=32.
// Intensity 64 FLOP/LDS-byte (vs 48) -> MFMA-dominant per-step balance.
// LDS: 48KB staging (A 2x8K + B 2x16K), aS overlay 64KB -> 2 blocks/CU.
// Echo B-frags read directly from L2-resident exT (no eT plane).
// 32x32 C/D layout: col=lane&31, row=(reg&3)+8*(reg>>2)+4*(lane>>5).
// ---------------------------------------------------------------------------
__global__ __launch_bounds__(256, 2)
void fused_mfma3(const unsigned short* __restrict__ spnF,  // [B][2048] hi|lo
                 const unsigned short* __restrict__ spnE,  // [N][2048] hi|lo
                 const unsigned short* __restrict__ exT,   // [64][N] bf16
                 float* __restrict__ echo,                 // [B][64] accum
                 float* __restrict__ rowsum,               // [B] accum
                 const int* __restrict__ p_ptr,
                 int N, int K)
{
    __shared__ __align__(16) unsigned char S[65536];
    unsigned char* sA_hi = S;            //  8KB: 128 rows x 64B
    unsigned char* sA_lo = S + 8192;
    unsigned char* sB_hi = S + 16384;    // 16KB: 256 rows x 64B
    unsigned char* sB_lo = S + 32768;    // ..48KB
    unsigned char* aS    = S;            // overlay: [128][512B] a-tile (64KB)

    const int tid  = threadIdx.x;
    const int lane = tid & 63;
    const int wave = tid >> 6;
    const int wr = wave >> 1, wc = wave & 1;
    const int l31 = lane & 31, hi = lane >> 5;
    const int brow  = blockIdx.x * 128;
    const int ncol0 = blockIdx.y * 512;
    const int p = p_ptr[0];
    const char* Af = (const char*)spnF + (size_t)brow * 4096;

    // pre-swizzled global source offsets (linear LDS dest <- swizzled src)
    int srcA[2], srcB[4];
#pragma unroll
    for (int q = 0; q < 2; ++q) {
        int t = tid + q * 256; int row = t >> 2;
        srcA[q] = row * 4096 + ((t & 3) ^ ((row >> 1) & 3)) * 16;
    }
#pragma unroll
    for (int q = 0; q < 4; ++q) {
        int t = tid + q * 256; int row = t >> 2;
        srcB[q] = row * 4096 + ((t & 3) ^ ((row >> 1) & 3)) * 16;
    }

    f32x16 acc_e[2] = {};
    const int nk = K / 32;

    for (int nt = 0; nt < 2; ++nt) {
        const int ncol = ncol0 + nt * 256;
        const char* Bn = (const char*)spnE + (size_t)ncol * 4096;

        // ---- s-tile GEMM (bf16x3, 32x32x16), single-buffer BK=32 ----
        f32x16 acc[2][4] = {};
        for (int k = 0; k < nk; ++k) {
            const int kb = k * 64;
#pragma unroll
            for (int q = 0; q < 2; ++q) {
                gload16(Af + srcA[q] + kb,        sA_hi + wave * 1024 + q * 4096);
                gload16(Af + srcA[q] + 2048 + kb, sA_lo + wave * 1024 + q * 4096);
            }
#pragma unroll
            for (int q = 0; q < 4; ++q) {
                gload16(Bn + srcB[q] + kb,        sB_hi + wave * 1024 + q * 4096);
                gload16(Bn + srcB[q] + 2048 + kb, sB_lo + wave * 1024 + q * 4096);
            }
            __syncthreads();
#pragma unroll
            for (int sl = 0; sl < 2; ++sl) {
                const int ch = sl * 2 + hi;
                short8 bh[4], bl[4];
#pragma unroll
                for (int fn = 0; fn < 4; ++fn) {
                    int rb = wc * 128 + fn * 32 + l31;
                    bh[fn] = read_frag32(sB_hi, rb, ch);
                    bl[fn] = read_frag32(sB_lo, rb, ch);
                }
#pragma unroll
                for (int fm = 0; fm < 2; ++fm) {
                    int ra = wr * 64 + fm * 32 + l31;
                    short8 ah = read_frag32(sA_hi, ra, ch);
                    short8 al = read_frag32(sA_lo, ra, ch);
#pragma unroll
                    for (int fn = 0; fn < 4; ++fn) {
                        acc[fm][fn] = __builtin_amdgcn_mfma_f32_32x32x16_bf16(ah, bh[fn], acc[fm][fn], 0, 0, 0);
                        acc[fm][fn] = __builtin_amdgcn_mfma_f32_32x32x16_bf16(ah, bl[fn], acc[fm][fn], 0, 0, 0);
                        acc[fm][fn] = __builtin_amdgcn_mfma_f32_32x32x16_bf16(al, bh[fn], acc[fm][fn], 0, 0, 0);
                    }
                }
            }
            __syncthreads();   // protect planes before next stage / aS overlay
        }

        // ---- activation -> aS (bf16, swizzled), rowsum reduce+atomic ----
#pragma unroll
        for (int fm = 0; fm < 2; ++fm)
#pragma unroll
            for (int reg = 0; reg < 16; ++reg) {
                int row = wr * 64 + fm * 32 + (reg & 3) + 8 * (reg >> 2) + 4 * hi;
                float rs = 0.f;
#pragma unroll
                for (int fn = 0; fn < 4; ++fn) {
                    int col = wc * 128 + fn * 32 + l31;
                    float s = acc[fm][fn][reg];
                    float a;
                    if (p == 3) a = s * s * s;
                    else        a = copysignf(powf(fabsf(s), (float)p), s);
                    rs += fabsf(a);
                    int byte = row * 512 + (((col >> 3) ^ (row & 7)) << 4) + (col & 7) * 2;
                    *reinterpret_cast<unsigned short*>(aS + byte) = f2bf_rne(a);
                }
                rs += __shfl_xor(rs, 1);
                rs += __shfl_xor(rs, 2);
                rs += __shfl_xor(rs, 4);
                rs += __shfl_xor(rs, 8);
                rs += __shfl_xor(rs, 16);
                if (l31 == 0) atomicAdd(&rowsum[brow + row], rs);
            }
        __syncthreads();   // aS writes visible

        // ---- echo mini-GEMM: acc_e += a[128][256] @ exR[256][64] ----
        // A from aS (swizzled); B direct from exT (L2-resident, 16B/lane).
#pragma unroll
        for (int ks = 0; ks < 16; ++ks) {
            int kn = ncol + ks * 16 + hi * 8;
            short8 bfr[2];
#pragma unroll
            for (int fn2 = 0; fn2 < 2; ++fn2) {
                int c = fn2 * 32 + l31;
                bfr[fn2] = *reinterpret_cast<const short8*>(exT + (size_t)c * N + kn);
            }
            int ra = wave * 32 + l31;
            int ch = ks * 2 + hi;
            int byte = ra * 512 + ((ch ^ (ra & 7)) << 4);
            short8 af = *reinterpret_cast<const short8*>(aS + byte);
#pragma unroll
            for (int fn2 = 0; fn2 < 2; ++fn2)
                acc_e[fn2] = __builtin_amdgcn_mfma_f32_32x32x16_bf16(af, bfr[fn2], acc_e[fn2], 0, 0, 0);
        }
        __syncthreads();   // protect aS before next nt restages
    }

    // ---- global accumulation: echo ----
#pragma unroll
    for (int fn2 = 0; fn2 < 2; ++fn2)
#pragma unroll
        for (int reg = 0; reg < 16; ++reg) {
            int row = brow + wave * 32 + (reg & 3) + 8 * (reg >> 2) + 4 * hi;
            int col = fn2 * 32 + l31;
            atomicAdd(&echo[(size_t)row * 64 + col], acc_e[fn2][reg]);
        }
}

// ---------------------------------------------------------------------------
// Finalize: echo /= max(rowsum,eps); neg_dists = -||echo - class_reps||;
// BCE-with-logits partial sums.
// ---------------------------------------------------------------------------
__global__ __launch_bounds__(256)
void finalize_kernel(const float* __restrict__ echo, const float* __restrict__ rowsum,
                     const float* __restrict__ class_reps,  // [L][C]
                     const float* __restrict__ labels,      // [B][L]
                     float* __restrict__ out,               // [1 + B*L]
                     float* __restrict__ loss_acc,
                     int B, int L, int C)
{
    extern __shared__ float cr[];          // L*C floats
    const int tid = threadIdx.x;
    for (int i = tid; i < L * C; i += 256) cr[i] = class_reps[i];
    __syncthreads();

    const int row = blockIdx.x * 256 + tid;
    float lsum = 0.f;
    if (row < B) {
        const float inv = 1.f / fmaxf(rowsum[row], EPSN);
        float e[64];
        const float4* er = reinterpret_cast<const float4*>(echo + (size_t)row * 64);
#pragma unroll
        for (int q = 0; q < 16; ++q) {
            float4 v = er[q];
            e[q * 4 + 0] = v.x * inv; e[q * 4 + 1] = v.y * inv;
            e[q * 4 + 2] = v.z * inv; e[q * 4 + 3] = v.w * inv;
        }
        for (int l = 0; l < L; ++l) {
            float d = 0.f;
#pragma unroll
            for (int c = 0; c < 64; ++c) {
                float t = e[c] - cr[l * 64 + c];
                d += t * t;
            }
            float x = -sqrtf(d);
            out[1 + (size_t)row * L + l] = x;
            float y = labels[(size_t)row * L + l];
            lsum += fmaxf(x, 0.f) - x * y + log1pf(expf(-fabsf(x)));
        }
    }
#pragma unroll
    for (int off = 32; off > 0; off >>= 1) lsum += __shfl_down(lsum, off);
    __shared__ float red[4];
    if ((tid & 63) == 0) red[tid >> 6] = lsum;
    __syncthreads();
    if (tid == 0) atomicAdd(loss_acc, red[0] + red[1] + red[2] + red[3]);
}

__global__ void write_loss(const float* __restrict__ loss_acc,
                           float* __restrict__ out, float invBL)
{
    out[0] = loss_acc[0] * invBL;
}

// ---------------------------------------------------------------------------
extern "C" void kernel_launch(void* const* d_in, const int* in_sizes, int n_in,
                              void* d_out, int out_size, void* d_ws, size_t ws_size,
                              hipStream_t stream)
{
    const float* features    = (const float*)d_in[0];   // [B][D]
    const float* labels      = (const float*)d_in[1];   // [B][L]
    const float* g_weight    = (const float*)d_in[2];   // [F][D]
    const float* ex_features = (const float*)d_in[3];   // [N][D]
    const float* ex_reps     = (const float*)d_in[4];   // [N][C]
    const float* class_reps  = (const float*)d_in[5];   // [L][C]
    const int*   p_ptr       = (const int*)d_in[6];

    const int D = 1024;
    const int B = in_sizes[0] / D;          // 4096
    const int F = in_sizes[2] / D;          // 1024
    const int N = in_sizes[3] / D;          // 8192
    const int C = in_sizes[4] / N;          // 64
    const int L = in_sizes[5] / C;          // 28

    // workspace layout (bytes)
    char* ws = (char*)d_ws;
    float*          Xf     = (float*)(ws);                            // B rows: fp32 then hi/lo in-place
    float*          Xe     = (float*)(ws + (size_t)B * 4096);         // N rows
    unsigned short* sp_w   = (unsigned short*)(ws + (size_t)(B + N) * 4096);           // F rows hi/lo
    unsigned short* exT    = (unsigned short*)(ws + (size_t)(B + N + F) * 4096);       // [64][N] bf16
    float*          echo   = (float*)(ws + (size_t)(B + N + F) * 4096 + (size_t)64 * N * 2);
    float*          rsums  = echo + (size_t)B * C;
    float*          loss_a = rsums + B;

    size_t base_end = (size_t)(B + N + F) * 4096 + (size_t)64 * N * 2
                    + ((size_t)B * C + B + 4) * 4;
    size_t scratch_off = (base_end + 255) & ~(size_t)255;
    size_t need = scratch_off + (size_t)N * 4096;   // N-row hi/lo scratch (reused)
    unsigned short* spA = (unsigned short*)(ws + scratch_off);
    const bool use_presplit = (ws_size >= need);

    hipMemsetAsync(echo, 0, (size_t)(B * C + B + 4) * 4, stream);

    // prep: split W, transpose exR
    split_rows<<<F, 256, 0, stream>>>(g_weight, sp_w);
    transpose_exR<<<N / 256, 256, 0, stream>>>(ex_reps, exT, N);

    // projections: X @ W^T (bf16x3 MFMA)
    if (use_presplit) {
        split_rows<<<N, 256, 0, stream>>>(ex_features, spA);
        {
            dim3 g2(F / 128, N / 128);
            gemm_ps<<<g2, 256, 0, stream>>>(spA, sp_w, Xe, F, D);
        }
        split_rows<<<B, 256, 0, stream>>>(features, spA);
        {
            dim3 g1(F / 128, B / 128);
            gemm_ps<<<g1, 256, 0, stream>>>(spA, sp_w, Xf, F, D);
        }
    } else {
        dim3 g1(F / 128, B / 128);
        gemm_w<<<g1, 256, 0, stream>>>(features, sp_w, Xf, F, D);
        dim3 g2(F / 128, N / 128);
        gemm_w<<<g2, 256, 0, stream>>>(ex_features, sp_w, Xe, F, D);
    }

    // L2 normalize + split in-place
    l2norm_split<<<B, 256, 0, stream>>>(Xf);
    l2norm_split<<<N, 256, 0, stream>>>(Xe);

    // fused cosine^p + L1-fold + exemplar readout (128x256 tile, 32x32 MFMA)
    {
        dim3 g(B / 128, N / 512);
        fused_mfma3<<<g, 256, 0, stream>>>((const unsigned short*)Xf,
                                           (const unsigned short*)Xe,
                                           exT, echo, rsums, p_ptr, N, F);
    }

    // finalize: neg_dists + loss
    {
        dim3 g((B + 255) / 256);
        size_t shb = (size_t)L * C * sizeof(float);
        finalize_kernel<<<g, 256, shb, stream>>>(echo, rsums, class_reps, labels,
                                                 (float*)d_out, loss_a, B, L, C);
    }
    write_loss<<<1, 1, 0, stream>>>(loss_a, (float*)d_out, 1.f / (float)(B * L));
}

// Round 10
// 1941.422 us; speedup vs baseline: 1.0010x; 1.0010x over previous
//
#include <hip/hip_runtime.h>
#include <math.h>

#define EPSN 1e-12f

typedef __attribute__((ext_vector_type(8))) short short8;
typedef __attribute__((ext_vector_type(4))) float f32x4;
typedef __attribute__((ext_vector_type(16))) float f32x16;

// ---------------------------------------------------------------------------
// helpers
// ---------------------------------------------------------------------------
__device__ __forceinline__ void split_hi_lo(float x, unsigned short& h, unsigned short& l)
{
    unsigned int xb = __float_as_uint(x);
    h = (unsigned short)(xb >> 16);
    float r = x - __uint_as_float(xb & 0xffff0000u);
    l = (unsigned short)(__float_as_uint(r) >> 16);
}

__device__ __forceinline__ unsigned short f2bf_rne(float x)
{
    unsigned int u = __float_as_uint(x);
    unsigned int r = u + 0x7fffu + ((u >> 16) & 1u);
    return (unsigned short)(r >> 16);
}

// async global->LDS, 16B per lane; LDS dest = wave-uniform base + lane*16
__device__ __forceinline__ void gload16(const void* g, void* l)
{
    __builtin_amdgcn_global_load_lds(
        (const __attribute__((address_space(1))) void*)g,
        (__attribute__((address_space(3))) void*)l, 16, 0, 0);
}

// ---- BK=64 plane helpers (gemm_w fallback) ----
__device__ __forceinline__ short8 read_frag(const unsigned char* plane, int row, int chunk)
{
    int byte = row * 128 + ((chunk ^ (row & 7)) << 4);
    return *reinterpret_cast<const short8*>(plane + byte);
}

__device__ __forceinline__ void stage_split(const float* __restrict__ src, int K, int k0,
                                            unsigned char* hi_plane, unsigned char* lo_plane,
                                            int tid)
{
#pragma unroll
    for (int q = 0; q < 8; ++q) {
        int idx = tid + q * 256;
        int row = idx >> 4;
        int f4  = idx & 15;
        float4 v = *reinterpret_cast<const float4*>(&src[(size_t)row * K + k0 + f4 * 4]);
        unsigned short h[4], l[4];
        split_hi_lo(v.x, h[0], l[0]);
        split_hi_lo(v.y, h[1], l[1]);
        split_hi_lo(v.z, h[2], l[2]);
        split_hi_lo(v.w, h[3], l[3]);
        int byte = row * 128 + (((f4 >> 1) ^ (row & 7)) << 4) + (f4 & 1) * 8;
        *reinterpret_cast<ushort4*>(hi_plane + byte) = make_ushort4(h[0], h[1], h[2], h[3]);
        *reinterpret_cast<ushort4*>(lo_plane + byte) = make_ushort4(l[0], l[1], l[2], l[3]);
    }
}

// ---- BK=32 64B-row plane helpers (gemm_ps + fused) ----
// rows 64B (32 bf16), 4 chunks; swizzle chunk^((row>>1)&3) -> ~2-way (free).
__device__ __forceinline__ short8 read_frag32(const unsigned char* plane, int row, int ch)
{
    int byte = row * 64 + ((ch ^ ((row >> 1) & 3)) << 4);
    return *reinterpret_cast<const short8*>(plane + byte);
}

// ---------------------------------------------------------------------------
// tiny prep kernels
// ---------------------------------------------------------------------------
__global__ __launch_bounds__(256)
void split_rows(const float* __restrict__ src, unsigned short* __restrict__ dst)
{
    const int row = blockIdx.x, tid = threadIdx.x;
    float4 v = reinterpret_cast<const float4*>(src + (size_t)row * 1024)[tid];
    unsigned short h[4], l[4];
    split_hi_lo(v.x, h[0], l[0]); split_hi_lo(v.y, h[1], l[1]);
    split_hi_lo(v.z, h[2], l[2]); split_hi_lo(v.w, h[3], l[3]);
    unsigned short* R = dst + (size_t)row * 2048;
    *reinterpret_cast<ushort4*>(R + tid * 4)        = make_ushort4(h[0], h[1], h[2], h[3]);
    *reinterpret_cast<ushort4*>(R + 1024 + tid * 4) = make_ushort4(l[0], l[1], l[2], l[3]);
}

__global__ __launch_bounds__(256)
void l2norm_split(float* __restrict__ X)
{
    const int row = blockIdx.x, tid = threadIdx.x;
    float* Xr = X + (size_t)row * 1024;
    float4 v = reinterpret_cast<float4*>(Xr)[tid];
    float s = v.x * v.x + v.y * v.y + v.z * v.z + v.w * v.w;
#pragma unroll
    for (int off = 32; off > 0; off >>= 1) s += __shfl_down(s, off);
    __shared__ float red[4];
    __shared__ float scale_sh;
    if ((tid & 63) == 0) red[tid >> 6] = s;
    __syncthreads();
    if (tid == 0) {
        float n = sqrtf(red[0] + red[1] + red[2] + red[3]);
        scale_sh = 1.f / fmaxf(n, EPSN);
    }
    __syncthreads();
    const float sc = scale_sh;
    v.x *= sc; v.y *= sc; v.z *= sc; v.w *= sc;
    unsigned short h[4], l[4];
    split_hi_lo(v.x, h[0], l[0]); split_hi_lo(v.y, h[1], l[1]);
    split_hi_lo(v.z, h[2], l[2]); split_hi_lo(v.w, h[3], l[3]);
    unsigned short* R = reinterpret_cast<unsigned short*>(Xr);
    *reinterpret_cast<ushort4*>(R + tid * 4)        = make_ushort4(h[0], h[1], h[2], h[3]);
    *reinterpret_cast<ushort4*>(R + 1024 + tid * 4) = make_ushort4(l[0], l[1], l[2], l[3]);
}

__global__ __launch_bounds__(256)
void transpose_exR(const float* __restrict__ exR, unsigned short* __restrict__ exT, int N)
{
    __shared__ unsigned short sm[64][256];
    const int tid = threadIdx.x;
    const int n0 = blockIdx.x * 256;
    const float4* src = reinterpret_cast<const float4*>(exR + (size_t)(n0 + tid) * 64);
#pragma unroll
    for (int q = 0; q < 16; ++q) {
        float4 v = src[q];
        sm[q * 4 + 0][tid] = f2bf_rne(v.x);
        sm[q * 4 + 1][tid] = f2bf_rne(v.y);
        sm[q * 4 + 2][tid] = f2bf_rne(v.z);
        sm[q * 4 + 3][tid] = f2bf_rne(v.w);
    }
    __syncthreads();
#pragma unroll
    for (int j = 0; j < 32; ++j) {
        int idx = tid + j * 256;
        int c = idx >> 7, nl2 = idx & 127;
        *reinterpret_cast<ushort2*>(exT + (size_t)c * N + n0 + nl2 * 2) =
            *reinterpret_cast<const ushort2*>(&sm[c][nl2 * 2]);
    }
}

// ---------------------------------------------------------------------------
// Pre-split projection GEMM (BK=32 dbuf, 16x16 MFMA) — proven
// ---------------------------------------------------------------------------
__device__ __forceinline__ void make_off32(int wave, int lane, int off32[2])
{
#pragma unroll
    for (int i = 0; i < 2; ++i) {
        int t   = (wave * 2 + i) * 64 + lane;
        int row = t >> 2;
        int cl  = t & 3;
        int cg  = cl ^ ((row >> 1) & 3);
        off32[i] = row * 4096 + cg * 16;
    }
}

__device__ __forceinline__ void stage32(const char* Ab, const char* Bb, int k2,
                                        unsigned char* buf, const int off32[2], int wave)
{
#pragma unroll
    for (int i = 0; i < 2; ++i) {
        unsigned char* d = buf + (wave * 2 + i) * 1024;
        gload16(Ab + off32[i] + k2,        d);             // A_hi
        gload16(Ab + off32[i] + 2048 + k2, d + 8192);      // A_lo
        gload16(Bb + off32[i] + k2,        d + 16384);     // B_hi
        gload16(Bb + off32[i] + 2048 + k2, d + 24576);     // B_lo
    }
}

__device__ __forceinline__ void compute32(const unsigned char* buf, int lane, int wr, int wc,
                                          f32x4 acc[4][4])
{
    const int ch = lane >> 4;
    short8 bh[4], bl[4];
#pragma unroll
    for (int fn = 0; fn < 4; ++fn) {
        int rb = wc * 64 + fn * 16 + (lane & 15);
        bh[fn] = read_frag32(buf + 16384, rb, ch);
        bl[fn] = read_frag32(buf + 24576, rb, ch);
    }
#pragma unroll
    for (int fm = 0; fm < 4; ++fm) {
        int ra = wr * 64 + fm * 16 + (lane & 15);
        short8 ah = read_frag32(buf,        ra, ch);
        short8 al = read_frag32(buf + 8192, ra, ch);
#pragma unroll
        for (int fn = 0; fn < 4; ++fn) {
            acc[fm][fn] = __builtin_amdgcn_mfma_f32_16x16x32_bf16(ah, bh[fn], acc[fm][fn], 0, 0, 0);
            acc[fm][fn] = __builtin_amdgcn_mfma_f32_16x16x32_bf16(ah, bl[fn], acc[fm][fn], 0, 0, 0);
            acc[fm][fn] = __builtin_amdgcn_mfma_f32_16x16x32_bf16(al, bh[fn], acc[fm][fn], 0, 0, 0);
        }
    }
}

__global__ __launch_bounds__(256, 2)
void gemm_ps(const unsigned short* __restrict__ spA, const unsigned short* __restrict__ spW,
             float* __restrict__ C, int Nn, int K)
{
    __shared__ __align__(16) unsigned char S[65536];

    const int tid  = threadIdx.x;
    const int lane = tid & 63;
    const int wave = tid >> 6;
    const int wr = wave >> 1, wc = wave & 1;
    const int brow = blockIdx.y * 128;
    const int bcol = blockIdx.x * 128;
    const char* Ab = (const char*)spA + (size_t)brow * 4096;
    const char* Wb = (const char*)spW + (size_t)bcol * 4096;

    int off32[2];
    make_off32(wave, lane, off32);

    f32x4 acc[4][4] = {};
    const int nk = K / 32;

    stage32(Ab, Wb, 0, S, off32, wave);
    __syncthreads();
    int cur = 0;
    for (int k = 0; k < nk; ++k) {
        if (k + 1 < nk)
            stage32(Ab, Wb, (k + 1) * 64, S + (cur ^ 1) * 32768, off32, wave);
        compute32(S + cur * 32768, lane, wr, wc, acc);
        __syncthreads();
        cur ^= 1;
    }

#pragma unroll
    for (int fm = 0; fm < 4; ++fm)
#pragma unroll
        for (int fn = 0; fn < 4; ++fn)
#pragma unroll
            for (int reg = 0; reg < 4; ++reg) {
                int row = brow + wr * 64 + fm * 16 + (lane >> 4) * 4 + reg;
                int col = bcol + wc * 64 + fn * 16 + (lane & 15);
                C[(size_t)row * Nn + col] = acc[fm][fn][reg];
            }
}

// ---------------------------------------------------------------------------
// Fallback projection GEMM (BK=64 single-buffer, reg-staged A split)
// ---------------------------------------------------------------------------
__global__ __launch_bounds__(256, 2)
void gemm_w(const float* __restrict__ A, const unsigned short* __restrict__ spW,
            float* __restrict__ C, int Nn, int K)
{
    __shared__ __align__(16) unsigned char smem[65536];
    unsigned char* sA_hi = smem;
    unsigned char* sA_lo = smem + 16384;
    unsigned char* sB_hi = smem + 32768;
    unsigned char* sB_lo = smem + 49152;

    const int tid  = threadIdx.x;
    const int lane = tid & 63;
    const int wave = tid >> 6;
    const int wr = wave >> 1, wc = wave & 1;
    const int brow = blockIdx.y * 128;
    const int bcol = blockIdx.x * 128;
    const float* Abase = A + (size_t)brow * K;
    const char*  Wbase = (const char*)spW + (size_t)bcol * 4096;

    int offW[4];
#pragma unroll
    for (int i = 0; i < 4; ++i) {
        int t = (wave * 4 + i) * 64 + lane;
        int r = t >> 3, c = (t & 7) ^ (r & 7);
        offW[i] = r * 4096 + c * 16;
    }

    f32x4 acc[4][4] = {};

    for (int k0 = 0; k0 < K; k0 += 64) {
        const int k2 = k0 * 2;
#pragma unroll
        for (int i = 0; i < 4; ++i) {
            gload16(Wbase + offW[i] + k2,        sB_hi + (wave * 4 + i) * 1024);
            gload16(Wbase + offW[i] + 2048 + k2, sB_lo + (wave * 4 + i) * 1024);
        }
        stage_split(Abase, K, k0, sA_hi, sA_lo, tid);
        __syncthreads();
#pragma unroll
        for (int kk = 0; kk < 2; ++kk) {
            const int ch = kk * 4 + (lane >> 4);
            short8 bh[4], bl[4];
#pragma unroll
            for (int fn = 0; fn < 4; ++fn) {
                int rb = wc * 64 + fn * 16 + (lane & 15);
                bh[fn] = read_frag(sB_hi, rb, ch);
                bl[fn] = read_frag(sB_lo, rb, ch);
            }
#pragma unroll
            for (int fm = 0; fm < 4; ++fm) {
                int ra = wr * 64 + fm * 16 + (lane & 15);
                short8 ah = read_frag(sA_hi, ra, ch);
                short8 al = read_frag(sA_lo, ra, ch);
#pragma unroll
                for (int fn = 0; fn < 4; ++fn) {
                    acc[fm][fn] = __builtin_amdgcn_mfma_f32_16x16x32_bf16(ah, bh[fn], acc[fm][fn], 0, 0, 0);
                    acc[fm][fn] = __builtin_amdgcn_mfma_f32_16x16x32_bf16(ah, bl[fn], acc[fm][fn], 0, 0, 0);
                    acc[fm][fn] = __builtin_amdgcn_mfma_f32_16x16x32_bf16(al, bh[fn], acc[fm][fn], 0, 0, 0);
                }
            }
        }
        __syncthreads();
    }

#pragma unroll
    for (int fm = 0; fm < 4; ++fm)
#pragma unroll
        for (int fn = 0; fn < 4; ++fn)
#pragma unroll
            for (int reg = 0; reg < 4; ++reg) {
                int row = brow + wr * 64 + fm * 16 + (lane >> 4) * 4 + reg;
                int col = bcol + wc * 64 + fn * 16 + (lane & 15);
                C[(size_t)row * Nn + col] = acc[fm][fn][reg];
            }
}

// ---------------------------------------------------------------------------
// Fused kernel v4 = v3 + per-nt acc_e flush (spill fix).
// Block 128x256, wave tile 64x128, 32x32x16 MFMA, BK=32 single-buffer.
// acc_e is zeroed/flushed per n-tile so it is NOT live across the s-GEMM,
// keeping peak live regs ~= acc(128) + working (~50) < 256-VGPR cap.
// ---------------------------------------------------------------------------
__global__ __launch_bounds__(256, 2)
void fused_mfma4(const unsigned short* __restrict__ spnF,  // [B][2048] hi|lo
                 const unsigned short* __restrict__ spnE,  // [N][2048] hi|lo
                 const unsigned short* __restrict__ exT,   // [64][N] bf16
                 float* __restrict__ echo,                 // [B][64] accum
                 float* __restrict__ rowsum,               // [B] accum
                 const int* __restrict__ p_ptr,
                 int N, int K)
{
    __shared__ __align__(16) unsigned char S[65536];
    unsigned char* sA_hi = S;            //  8KB: 128 rows x 64B
    unsigned char* sA_lo = S + 8192;
    unsigned char* sB_hi = S + 16384;    // 16KB: 256 rows x 64B
    unsigned char* sB_lo = S + 32768;    // ..48KB
    unsigned char* aS    = S;            // overlay: [128][512B] a-tile (64KB)

    const int tid  = threadIdx.x;
    const int lane = tid & 63;
    const int wave = tid >> 6;
    const int wr = wave >> 1, wc = wave & 1;
    const int l31 = lane & 31, hi = lane >> 5;
    const int brow  = blockIdx.x * 128;
    const int ncol0 = blockIdx.y * 512;
    const int p = p_ptr[0];
    const char* Af = (const char*)spnF + (size_t)brow * 4096;

    // pre-swizzled global source offsets (linear LDS dest <- swizzled src)
    int srcA[2], srcB[4];
#pragma unroll
    for (int q = 0; q < 2; ++q) {
        int t = tid + q * 256; int row = t >> 2;
        srcA[q] = row * 4096 + ((t & 3) ^ ((row >> 1) & 3)) * 16;
    }
#pragma unroll
    for (int q = 0; q < 4; ++q) {
        int t = tid + q * 256; int row = t >> 2;
        srcB[q] = row * 4096 + ((t & 3) ^ ((row >> 1) & 3)) * 16;
    }

    const int nk = K / 32;

    for (int nt = 0; nt < 2; ++nt) {
        const int ncol = ncol0 + nt * 256;
        const char* Bn = (const char*)spnE + (size_t)ncol * 4096;

        // ---- s-tile GEMM (bf16x3, 32x32x16), single-buffer BK=32 ----
        f32x16 acc[2][4] = {};
        for (int k = 0; k < nk; ++k) {
            const int kb = k * 64;
#pragma unroll
            for (int q = 0; q < 2; ++q) {
                gload16(Af + srcA[q] + kb,        sA_hi + wave * 1024 + q * 4096);
                gload16(Af + srcA[q] + 2048 + kb, sA_lo + wave * 1024 + q * 4096);
            }
#pragma unroll
            for (int q = 0; q < 4; ++q) {
                gload16(Bn + srcB[q] + kb,        sB_hi + wave * 1024 + q * 4096);
                gload16(Bn + srcB[q] + 2048 + kb, sB_lo + wave * 1024 + q * 4096);
            }
            __syncthreads();
#pragma unroll
            for (int sl = 0; sl < 2; ++sl) {
                const int ch = sl * 2 + hi;
                short8 bh[4], bl[4];
#pragma unroll
                for (int fn = 0; fn < 4; ++fn) {
                    int rb = wc * 128 + fn * 32 + l31;
                    bh[fn] = read_frag32(sB_hi, rb, ch);
                    bl[fn] = read_frag32(sB_lo, rb, ch);
                }
#pragma unroll
                for (int fm = 0; fm < 2; ++fm) {
                    int ra = wr * 64 + fm * 32 + l31;
                    short8 ah = read_frag32(sA_hi, ra, ch);
                    short8 al = read_frag32(sA_lo, ra, ch);
#pragma unroll
                    for (int fn = 0; fn < 4; ++fn) {
                        acc[fm][fn] = __builtin_amdgcn_mfma_f32_32x32x16_bf16(ah, bh[fn], acc[fm][fn], 0, 0, 0);
                        acc[fm][fn] = __builtin_amdgcn_mfma_f32_32x32x16_bf16(ah, bl[fn], acc[fm][fn], 0, 0, 0);
                        acc[fm][fn] = __builtin_amdgcn_mfma_f32_32x32x16_bf16(al, bh[fn], acc[fm][fn], 0, 0, 0);
                    }
                }
            }
            __syncthreads();   // protect planes before next stage / aS overlay
        }

        // ---- activation -> aS (bf16, swizzled), rowsum reduce+atomic ----
#pragma unroll
        for (int fm = 0; fm < 2; ++fm)
#pragma unroll
            for (int reg = 0; reg < 16; ++reg) {
                int row = wr * 64 + fm * 32 + (reg & 3) + 8 * (reg >> 2) + 4 * hi;
                float rs = 0.f;
#pragma unroll
                for (int fn = 0; fn < 4; ++fn) {
                    int col = wc * 128 + fn * 32 + l31;
                    float s = acc[fm][fn][reg];
                    float a;
                    if (p == 3) a = s * s * s;
                    else        a = copysignf(powf(fabsf(s), (float)p), s);
                    rs += fabsf(a);
                    int byte = row * 512 + (((col >> 3) ^ (row & 7)) << 4) + (col & 7) * 2;
                    *reinterpret_cast<unsigned short*>(aS + byte) = f2bf_rne(a);
                }
                rs += __shfl_xor(rs, 1);
                rs += __shfl_xor(rs, 2);
                rs += __shfl_xor(rs, 4);
                rs += __shfl_xor(rs, 8);
                rs += __shfl_xor(rs, 16);
                if (l31 == 0) atomicAdd(&rowsum[brow + row], rs);
            }
        __syncthreads();   // aS writes visible

        // ---- echo mini-GEMM (per-nt accumulator, flushed immediately) ----
        // A from aS (swizzled); B direct from exT (L2-resident, 16B/lane).
        f32x16 acc_e[2] = {};
#pragma unroll
        for (int ks = 0; ks < 16; ++ks) {
            int kn = ncol + ks * 16 + hi * 8;
            short8 bfr[2];
#pragma unroll
            for (int fn2 = 0; fn2 < 2; ++fn2) {
                int c = fn2 * 32 + l31;
                bfr[fn2] = *reinterpret_cast<const short8*>(exT + (size_t)c * N + kn);
            }
            int ra = wave * 32 + l31;
            int ch = ks * 2 + hi;
            int byte = ra * 512 + ((ch ^ (ra & 7)) << 4);
            short8 af = *reinterpret_cast<const short8*>(aS + byte);
#pragma unroll
            for (int fn2 = 0; fn2 < 2; ++fn2)
                acc_e[fn2] = __builtin_amdgcn_mfma_f32_32x32x16_bf16(af, bfr[fn2], acc_e[fn2], 0, 0, 0);
        }

        // flush echo partials now so acc_e is dead during the next s-GEMM
#pragma unroll
        for (int fn2 = 0; fn2 < 2; ++fn2)
#pragma unroll
            for (int reg = 0; reg < 16; ++reg) {
                int row = brow + wave * 32 + (reg & 3) + 8 * (reg >> 2) + 4 * hi;
                int col = fn2 * 32 + l31;
                atomicAdd(&echo[(size_t)row * 64 + col], acc_e[fn2][reg]);
            }
        __syncthreads();   // protect aS before next nt restages
    }
}

// ---------------------------------------------------------------------------
// Finalize: echo /= max(rowsum,eps); neg_dists = -||echo - class_reps||;
// BCE-with-logits partial sums.
// ---------------------------------------------------------------------------
__global__ __launch_bounds__(256)
void finalize_kernel(const float* __restrict__ echo, const float* __restrict__ rowsum,
                     const float* __restrict__ class_reps,  // [L][C]
                     const float* __restrict__ labels,      // [B][L]
                     float* __restrict__ out,               // [1 + B*L]
                     float* __restrict__ loss_acc,
                     int B, int L, int C)
{
    extern __shared__ float cr[];          // L*C floats
    const int tid = threadIdx.x;
    for (int i = tid; i < L * C; i += 256) cr[i] = class_reps[i];
    __syncthreads();

    const int row = blockIdx.x * 256 + tid;
    float lsum = 0.f;
    if (row < B) {
        const float inv = 1.f / fmaxf(rowsum[row], EPSN);
        float e[64];
        const float4* er = reinterpret_cast<const float4*>(echo + (size_t)row * 64);
#pragma unroll
        for (int q = 0; q < 16; ++q) {
            float4 v = er[q];
            e[q * 4 + 0] = v.x * inv; e[q * 4 + 1] = v.y * inv;
            e[q * 4 + 2] = v.z * inv; e[q * 4 + 3] = v.w * inv;
        }
        for (int l = 0; l < L; ++l) {
            float d = 0.f;
#pragma unroll
            for (int c = 0; c < 64; ++c) {
                float t = e[c] - cr[l * 64 + c];
                d += t * t;
            }
            float x = -sqrtf(d);
            out[1 + (size_t)row * L + l] = x;
            float y = labels[(size_t)row * L + l];
            lsum += fmaxf(x, 0.f) - x * y + log1pf(expf(-fabsf(x)));
        }
    }
#pragma unroll
    for (int off = 32; off > 0; off >>= 1) lsum += __shfl_down(lsum, off);
    __shared__ float red[4];
    if ((tid & 63) == 0) red[tid >> 6] = lsum;
    __syncthreads();
    if (tid == 0) atomicAdd(loss_acc, red[0] + red[1] + red[2] + red[3]);
}

__global__ void write_loss(const float* __restrict__ loss_acc,
                           float* __restrict__ out, float invBL)
{
    out[0] = loss_acc[0] * invBL;
}

// ---------------------------------------------------------------------------
extern "C" void kernel_launch(void* const* d_in, const int* in_sizes, int n_in,
                              void* d_out, int out_size, void* d_ws, size_t ws_size,
                              hipStream_t stream)
{
    const float* features    = (const float*)d_in[0];   // [B][D]
    const float* labels      = (const float*)d_in[1];   // [B][L]
    const float* g_weight    = (const float*)d_in[2];   // [F][D]
    const float* ex_features = (const float*)d_in[3];   // [N][D]
    const float* ex_reps     = (const float*)d_in[4];   // [N][C]
    const float* class_reps  = (const float*)d_in[5];   // [L][C]
    const int*   p_ptr       = (const int*)d_in[6];

    const int D = 1024;
    const int B = in_sizes[0] / D;          // 4096
    const int F = in_sizes[2] / D;          // 1024
    const int N = in_sizes[3] / D;          // 8192
    const int C = in_sizes[4] / N;          // 64
    const int L = in_sizes[5] / C;          // 28

    // workspace layout (bytes)
    char* ws = (char*)d_ws;
    float*          Xf     = (float*)(ws);                            // B rows: fp32 then hi/lo in-place
    float*          Xe     = (float*)(ws + (size_t)B * 4096);         // N rows
    unsigned short* sp_w   = (unsigned short*)(ws + (size_t)(B + N) * 4096);           // F rows hi/lo
    unsigned short* exT    = (unsigned short*)(ws + (size_t)(B + N + F) * 4096);       // [64][N] bf16
    float*          echo   = (float*)(ws + (size_t)(B + N + F) * 4096 + (size_t)64 * N * 2);
    float*          rsums  = echo + (size_t)B * C;
    float*          loss_a = rsums + B;

    size_t base_end = (size_t)(B + N + F) * 4096 + (size_t)64 * N * 2
                    + ((size_t)B * C + B + 4) * 4;
    size_t scratch_off = (base_end + 255) & ~(size_t)255;
    size_t need = scratch_off + (size_t)N * 4096;   // N-row hi/lo scratch (reused)
    unsigned short* spA = (unsigned short*)(ws + scratch_off);
    const bool use_presplit = (ws_size >= need);

    hipMemsetAsync(echo, 0, (size_t)(B * C + B + 4) * 4, stream);

    // prep: split W, transpose exR
    split_rows<<<F, 256, 0, stream>>>(g_weight, sp_w);
    transpose_exR<<<N / 256, 256, 0, stream>>>(ex_reps, exT, N);

    // projections: X @ W^T (bf16x3 MFMA)
    if (use_presplit) {
        split_rows<<<N, 256, 0, stream>>>(ex_features, spA);
        {
            dim3 g2(F / 128, N / 128);
            gemm_ps<<<g2, 256, 0, stream>>>(spA, sp_w, Xe, F, D);
        }
        split_rows<<<B, 256, 0, stream>>>(features, spA);
        {
            dim3 g1(F / 128, B / 128);
            gemm_ps<<<g1, 256, 0, stream>>>(spA, sp_w, Xf, F, D);
        }
    } else {
        dim3 g1(F / 128, B / 128);
        gemm_w<<<g1, 256, 0, stream>>>(features, sp_w, Xf, F, D);
        dim3 g2(F / 128, N / 128);
        gemm_w<<<g2, 256, 0, stream>>>(ex_features, sp_w, Xe, F, D);
    }

    // L2 normalize + split in-place
    l2norm_split<<<B, 256, 0, stream>>>(Xf);
    l2norm_split<<<N, 256, 0, stream>>>(Xe);

    // fused cosine^p + L1-fold + exemplar readout (128x256 tile, 32x32 MFMA)
    {
        dim3 g(B / 128, N / 512);
        fused_mfma4<<<g, 256, 0, stream>>>((const unsigned short*)Xf,
                                           (const unsigned short*)Xe,
                                           exT, echo, rsums, p_ptr, N, F);
    }

    // finalize: neg_dists + loss
    {
        dim3 g((B + 255) / 256);
        size_t shb = (size_t)L * C * sizeof(float);
        finalize_kernel<<<g, 256, shb, stream>>>(echo, rsums, class_reps, labels,
                                                 (float*)d_out, loss_a, B, L, C);
    }
    write_loss<<<1, 1, 0, stream>>>(loss_a, (float*)d_out, 1.f / (float)(B * L));
}

// Round 13
// 1597.539 us; speedup vs baseline: 1.2165x; 1.2153x over previous
//
#include <hip/hip_runtime.h>
#include <math.h>

#define EPSN 1e-12f

typedef __attribute__((ext_vector_type(8))) short short8;
typedef __attribute__((ext_vector_type(4))) float f32x4;

// ---------------------------------------------------------------------------
// helpers
// ---------------------------------------------------------------------------
__device__ __forceinline__ void split_hi_lo(float x, unsigned short& h, unsigned short& l)
{
    unsigned int xb = __float_as_uint(x);
    h = (unsigned short)(xb >> 16);
    float r = x - __uint_as_float(xb & 0xffff0000u);
    l = (unsigned short)(__float_as_uint(r) >> 16);
}

__device__ __forceinline__ unsigned short f2bf_rne(float x)
{
    unsigned int u = __float_as_uint(x);
    unsigned int r = u + 0x7fffu + ((u >> 16) & 1u);
    return (unsigned short)(r >> 16);
}

// async global->LDS, 16B per lane; LDS dest = wave-uniform base + lane*16
__device__ __forceinline__ void gload16(const void* g, void* l)
{
    __builtin_amdgcn_global_load_lds(
        (const __attribute__((address_space(1))) void*)g,
        (__attribute__((address_space(3))) void*)l, 16, 0, 0);
}

// ---- BK=64 plane helpers (gemm_w) ----
__device__ __forceinline__ short8 read_frag(const unsigned char* plane, int row, int chunk)
{
    int byte = row * 128 + ((chunk ^ (row & 7)) << 4);
    return *reinterpret_cast<const short8*>(plane + byte);
}

__device__ __forceinline__ void stage_split(const float* __restrict__ src, int K, int k0,
                                            unsigned char* hi_plane, unsigned char* lo_plane,
                                            int tid)
{
#pragma unroll
    for (int q = 0; q < 8; ++q) {
        int idx = tid + q * 256;
        int row = idx >> 4;
        int f4  = idx & 15;
        float4 v = *reinterpret_cast<const float4*>(&src[(size_t)row * K + k0 + f4 * 4]);
        unsigned short h[4], l[4];
        split_hi_lo(v.x, h[0], l[0]);
        split_hi_lo(v.y, h[1], l[1]);
        split_hi_lo(v.z, h[2], l[2]);
        split_hi_lo(v.w, h[3], l[3]);
        int byte = row * 128 + (((f4 >> 1) ^ (row & 7)) << 4) + (f4 & 1) * 8;
        *reinterpret_cast<ushort4*>(hi_plane + byte) = make_ushort4(h[0], h[1], h[2], h[3]);
        *reinterpret_cast<ushort4*>(lo_plane + byte) = make_ushort4(l[0], l[1], l[2], l[3]);
    }
}

// ---- BK=32 64B-row plane helpers (fused v5) ----
// rows 64B (32 bf16), 4 chunks; swizzle chunk^((row>>1)&3) -> ~2-way (free).
__device__ __forceinline__ short8 read_frag32(const unsigned char* plane, int row, int ch)
{
    int byte = row * 64 + ((ch ^ ((row >> 1) & 3)) << 4);
    return *reinterpret_cast<const short8*>(plane + byte);
}

// ---------------------------------------------------------------------------
// tiny prep kernels
// ---------------------------------------------------------------------------
__global__ __launch_bounds__(256)
void split_rows(const float* __restrict__ src, unsigned short* __restrict__ dst)
{
    const int row = blockIdx.x, tid = threadIdx.x;
    float4 v = reinterpret_cast<const float4*>(src + (size_t)row * 1024)[tid];
    unsigned short h[4], l[4];
    split_hi_lo(v.x, h[0], l[0]); split_hi_lo(v.y, h[1], l[1]);
    split_hi_lo(v.z, h[2], l[2]); split_hi_lo(v.w, h[3], l[3]);
    unsigned short* R = dst + (size_t)row * 2048;
    *reinterpret_cast<ushort4*>(R + tid * 4)        = make_ushort4(h[0], h[1], h[2], h[3]);
    *reinterpret_cast<ushort4*>(R + 1024 + tid * 4) = make_ushort4(l[0], l[1], l[2], l[3]);
}

__global__ __launch_bounds__(256)
void l2norm_split(float* __restrict__ X)
{
    const int row = blockIdx.x, tid = threadIdx.x;
    float* Xr = X + (size_t)row * 1024;
    float4 v = reinterpret_cast<float4*>(Xr)[tid];
    float s = v.x * v.x + v.y * v.y + v.z * v.z + v.w * v.w;
#pragma unroll
    for (int off = 32; off > 0; off >>= 1) s += __shfl_down(s, off);
    __shared__ float red[4];
    __shared__ float scale_sh;
    if ((tid & 63) == 0) red[tid >> 6] = s;
    __syncthreads();
    if (tid == 0) {
        float n = sqrtf(red[0] + red[1] + red[2] + red[3]);
        scale_sh = 1.f / fmaxf(n, EPSN);
    }
    __syncthreads();
    const float sc = scale_sh;
    v.x *= sc; v.y *= sc; v.z *= sc; v.w *= sc;
    unsigned short h[4], l[4];
    split_hi_lo(v.x, h[0], l[0]); split_hi_lo(v.y, h[1], l[1]);
    split_hi_lo(v.z, h[2], l[2]); split_hi_lo(v.w, h[3], l[3]);
    unsigned short* R = reinterpret_cast<unsigned short*>(Xr);
    *reinterpret_cast<ushort4*>(R + tid * 4)        = make_ushort4(h[0], h[1], h[2], h[3]);
    *reinterpret_cast<ushort4*>(R + 1024 + tid * 4) = make_ushort4(l[0], l[1], l[2], l[3]);
}

__global__ __launch_bounds__(256)
void transpose_exR(const float* __restrict__ exR, unsigned short* __restrict__ exT, int N)
{
    __shared__ unsigned short sm[64][256];
    const int tid = threadIdx.x;
    const int n0 = blockIdx.x * 256;
    const float4* src = reinterpret_cast<const float4*>(exR + (size_t)(n0 + tid) * 64);
#pragma unroll
    for (int q = 0; q < 16; ++q) {
        float4 v = src[q];
        sm[q * 4 + 0][tid] = f2bf_rne(v.x);
        sm[q * 4 + 1][tid] = f2bf_rne(v.y);
        sm[q * 4 + 2][tid] = f2bf_rne(v.z);
        sm[q * 4 + 3][tid] = f2bf_rne(v.w);
    }
    __syncthreads();
#pragma unroll
    for (int j = 0; j < 32; ++j) {
        int idx = tid + j * 256;
        int c = idx >> 7, nl2 = idx & 127;
        *reinterpret_cast<ushort2*>(exT + (size_t)c * N + n0 + nl2 * 2) =
            *reinterpret_cast<const ushort2*>(&sm[c][nl2 * 2]);
    }
}

// ---------------------------------------------------------------------------
// Projection GEMM (round-5 proven config: BK=64 single-buffer, reg-staged A)
// ---------------------------------------------------------------------------
__global__ __launch_bounds__(256, 2)
void gemm_w(const float* __restrict__ A, const unsigned short* __restrict__ spW,
            float* __restrict__ C, int Nn, int K)
{
    __shared__ __align__(16) unsigned char smem[65536];
    unsigned char* sA_hi = smem;
    unsigned char* sA_lo = smem + 16384;
    unsigned char* sB_hi = smem + 32768;
    unsigned char* sB_lo = smem + 49152;

    const int tid  = threadIdx.x;
    const int lane = tid & 63;
    const int wave = tid >> 6;
    const int wr = wave >> 1, wc = wave & 1;
    const int brow = blockIdx.y * 128;
    const int bcol = blockIdx.x * 128;
    const float* Abase = A + (size_t)brow * K;
    const char*  Wbase = (const char*)spW + (size_t)bcol * 4096;

    int offW[4];
#pragma unroll
    for (int i = 0; i < 4; ++i) {
        int t = (wave * 4 + i) * 64 + lane;
        int r = t >> 3, c = (t & 7) ^ (r & 7);
        offW[i] = r * 4096 + c * 16;
    }

    f32x4 acc[4][4] = {};

    for (int k0 = 0; k0 < K; k0 += 64) {
        const int k2 = k0 * 2;
#pragma unroll
        for (int i = 0; i < 4; ++i) {
            gload16(Wbase + offW[i] + k2,        sB_hi + (wave * 4 + i) * 1024);
            gload16(Wbase + offW[i] + 2048 + k2, sB_lo + (wave * 4 + i) * 1024);
        }
        stage_split(Abase, K, k0, sA_hi, sA_lo, tid);
        __syncthreads();
#pragma unroll
        for (int kk = 0; kk < 2; ++kk) {
            const int ch = kk * 4 + (lane >> 4);
            short8 bh[4], bl[4];
#pragma unroll
            for (int fn = 0; fn < 4; ++fn) {
                int rb = wc * 64 + fn * 16 + (lane & 15);
                bh[fn] = read_frag(sB_hi, rb, ch);
                bl[fn] = read_frag(sB_lo, rb, ch);
            }
#pragma unroll
            for (int fm = 0; fm < 4; ++fm) {
                int ra = wr * 64 + fm * 16 + (lane & 15);
                short8 ah = read_frag(sA_hi, ra, ch);
                short8 al = read_frag(sA_lo, ra, ch);
#pragma unroll
                for (int fn = 0; fn < 4; ++fn) {
                    acc[fm][fn] = __builtin_amdgcn_mfma_f32_16x16x32_bf16(ah, bh[fn], acc[fm][fn], 0, 0, 0);
                    acc[fm][fn] = __builtin_amdgcn_mfma_f32_16x16x32_bf16(ah, bl[fn], acc[fm][fn], 0, 0, 0);
                    acc[fm][fn] = __builtin_amdgcn_mfma_f32_16x16x32_bf16(al, bh[fn], acc[fm][fn], 0, 0, 0);
                }
            }
        }
        __syncthreads();
    }

#pragma unroll
    for (int fm = 0; fm < 4; ++fm)
#pragma unroll
        for (int fn = 0; fn < 4; ++fn)
#pragma unroll
            for (int reg = 0; reg < 4; ++reg) {
                int row = brow + wr * 64 + fm * 16 + (lane >> 4) * 4 + reg;
                int col = bcol + wc * 64 + fn * 16 + (lane & 15);
                C[(size_t)row * Nn + col] = acc[fm][fn][reg];
            }
}

// ---------------------------------------------------------------------------
// Fused kernel v5: block 128x256, 4 waves, wave tile 64x128, 16x16x32 MFMA,
// f32x4 accumulators (32 four-wide tuples — allocator-friendly, unlike the
// f32x16 tuples that spilled in v3/v4). BK=32 single-buffer staging (48KB),
// aS overlay 64KB -> 2 blocks/CU. Echo B-frags direct from L2-resident exT.
// ---------------------------------------------------------------------------
__global__ __launch_bounds__(256, 2)
void fused_mfma5(const unsigned short* __restrict__ spnF,  // [B][2048] hi|lo
                 const unsigned short* __restrict__ spnE,  // [N][2048] hi|lo
                 const unsigned short* __restrict__ exT,   // [64][N] bf16
                 float* __restrict__ echo,                 // [B][64] accum
                 float* __restrict__ rowsum,               // [B] accum
                 const int* __restrict__ p_ptr,
                 int N, int K)
{
    __shared__ __align__(16) unsigned char S[65536];
    unsigned char* sA_hi = S;            //  8KB: 128 rows x 64B
    unsigned char* sA_lo = S + 8192;
    unsigned char* sB_hi = S + 16384;    // 16KB: 256 rows x 64B
    unsigned char* sB_lo = S + 32768;    // ..48KB
    unsigned char* aS    = S;            // overlay: [128][512B] a-tile (64KB)

    const int tid  = threadIdx.x;
    const int lane = tid & 63;
    const int wave = tid >> 6;
    const int wr = wave >> 1, wc = wave & 1;   // 2x2 wave grid over 128x256
    const int l15 = lane & 15, lh = lane >> 4; // 16x16 frag lane split
    const int brow  = blockIdx.x * 128;
    const int ncol0 = blockIdx.y * 512;
    const int p = p_ptr[0];
    const char* Af = (const char*)spnF + (size_t)brow * 4096;

    // pre-swizzled global source offsets (linear LDS dest <- swizzled src)
    int srcA[2], srcB[4];
#pragma unroll
    for (int q = 0; q < 2; ++q) {
        int t = tid + q * 256; int row = t >> 2;
        srcA[q] = row * 4096 + ((t & 3) ^ ((row >> 1) & 3)) * 16;
    }
#pragma unroll
    for (int q = 0; q < 4; ++q) {
        int t = tid + q * 256; int row = t >> 2;
        srcB[q] = row * 4096 + ((t & 3) ^ ((row >> 1) & 3)) * 16;
    }

    const int nk = K / 32;

    for (int nt = 0; nt < 2; ++nt) {
        const int ncol = ncol0 + nt * 256;
        const char* Bn = (const char*)spnE + (size_t)ncol * 4096;

        // ---- s-tile GEMM (bf16x3, 16x16x32), single-buffer BK=32 ----
        f32x4 acc[4][8] = {};
        for (int k = 0; k < nk; ++k) {
            const int kb = k * 64;
#pragma unroll
            for (int q = 0; q < 2; ++q) {
                gload16(Af + srcA[q] + kb,        sA_hi + wave * 1024 + q * 4096);
                gload16(Af + srcA[q] + 2048 + kb, sA_lo + wave * 1024 + q * 4096);
            }
#pragma unroll
            for (int q = 0; q < 4; ++q) {
                gload16(Bn + srcB[q] + kb,        sB_hi + wave * 1024 + q * 4096);
                gload16(Bn + srcB[q] + 2048 + kb, sB_lo + wave * 1024 + q * 4096);
            }
            __syncthreads();

            // cache A frags (4 x 2 planes = 32 regs), stream B
            short8 ah[4], al[4];
#pragma unroll
            for (int fm = 0; fm < 4; ++fm) {
                int ra = wr * 64 + fm * 16 + l15;
                ah[fm] = read_frag32(sA_hi, ra, lh);
                al[fm] = read_frag32(sA_lo, ra, lh);
            }
#pragma unroll
            for (int fn = 0; fn < 8; ++fn) {
                int rb = wc * 128 + fn * 16 + l15;
                short8 bh = read_frag32(sB_hi, rb, lh);
                short8 bl = read_frag32(sB_lo, rb, lh);
#pragma unroll
                for (int fm = 0; fm < 4; ++fm) {
                    acc[fm][fn] = __builtin_amdgcn_mfma_f32_16x16x32_bf16(ah[fm], bh, acc[fm][fn], 0, 0, 0);
                    acc[fm][fn] = __builtin_amdgcn_mfma_f32_16x16x32_bf16(ah[fm], bl, acc[fm][fn], 0, 0, 0);
                    acc[fm][fn] = __builtin_amdgcn_mfma_f32_16x16x32_bf16(al[fm], bh, acc[fm][fn], 0, 0, 0);
                }
            }
            __syncthreads();   // protect planes before next stage / aS overlay
        }

        // ---- activation -> aS (bf16, swizzled), rowsum reduce+atomic ----
#pragma unroll
        for (int fm = 0; fm < 4; ++fm)
#pragma unroll
            for (int reg = 0; reg < 4; ++reg) {
                int row = wr * 64 + fm * 16 + lh * 4 + reg;
                float rs = 0.f;
#pragma unroll
                for (int fn = 0; fn < 8; ++fn) {
                    int col = wc * 128 + fn * 16 + l15;
                    float s = acc[fm][fn][reg];
                    float a;
                    if (p == 3) a = s * s * s;
                    else        a = copysignf(powf(fabsf(s), (float)p), s);
                    rs += fabsf(a);
                    int byte = row * 512 + (((col >> 3) ^ (row & 7)) << 4) + (col & 7) * 2;
                    *reinterpret_cast<unsigned short*>(aS + byte) = f2bf_rne(a);
                }
                rs += __shfl_xor(rs, 1);
                rs += __shfl_xor(rs, 2);
                rs += __shfl_xor(rs, 4);
                rs += __shfl_xor(rs, 8);
                if (l15 == 0) atomicAdd(&rowsum[brow + row], rs);
            }
        __syncthreads();   // aS writes visible

        // ---- echo mini-GEMM: echo[128][64] += a[128][256] @ exR[256][64] ----
        // wave owns rows wave*32..+31 (2 m-frags); B direct from exT.
        f32x4 acc_e[2][4] = {};
#pragma unroll
        for (int ks = 0; ks < 8; ++ks) {
            int kn = ncol + ks * 32 + lh * 8;
            short8 bfr[4];
#pragma unroll
            for (int fn2 = 0; fn2 < 4; ++fn2) {
                int c = fn2 * 16 + l15;
                bfr[fn2] = *reinterpret_cast<const short8*>(exT + (size_t)c * N + kn);
            }
#pragma unroll
            for (int fm2 = 0; fm2 < 2; ++fm2) {
                int ra = wave * 32 + fm2 * 16 + l15;
                int ch2 = ks * 4 + lh;
                int byte = ra * 512 + ((ch2 ^ (ra & 7)) << 4);
                short8 af = *reinterpret_cast<const short8*>(aS + byte);
#pragma unroll
                for (int fn2 = 0; fn2 < 4; ++fn2)
                    acc_e[fm2][fn2] = __builtin_amdgcn_mfma_f32_16x16x32_bf16(af, bfr[fn2], acc_e[fm2][fn2], 0, 0, 0);
            }
        }

        // flush echo partials so acc_e is dead during the next s-GEMM
#pragma unroll
        for (int fm2 = 0; fm2 < 2; ++fm2)
#pragma unroll
            for (int fn2 = 0; fn2 < 4; ++fn2)
#pragma unroll
                for (int reg = 0; reg < 4; ++reg) {
                    int row = brow + wave * 32 + fm2 * 16 + lh * 4 + reg;
                    int col = fn2 * 16 + l15;
                    atomicAdd(&echo[(size_t)row * 64 + col], acc_e[fm2][fn2][reg]);
                }
        __syncthreads();   // protect aS before next nt restages
    }
}

// ---------------------------------------------------------------------------
// Finalize: echo /= max(rowsum,eps); neg_dists = -||echo - class_reps||;
// BCE-with-logits partial sums.
// ---------------------------------------------------------------------------
__global__ __launch_bounds__(256)
void finalize_kernel(const float* __restrict__ echo, const float* __restrict__ rowsum,
                     const float* __restrict__ class_reps,  // [L][C]
                     const float* __restrict__ labels,      // [B][L]
                     float* __restrict__ out,               // [1 + B*L]
                     float* __restrict__ loss_acc,
                     int B, int L, int C)
{
    extern __shared__ float cr[];          // L*C floats
    const int tid = threadIdx.x;
    for (int i = tid; i < L * C; i += 256) cr[i] = class_reps[i];
    __syncthreads();

    const int row = blockIdx.x * 256 + tid;
    float lsum = 0.f;
    if (row < B) {
        const float inv = 1.f / fmaxf(rowsum[row], EPSN);
        float e[64];
        const float4* er = reinterpret_cast<const float4*>(echo + (size_t)row * 64);
#pragma unroll
        for (int q = 0; q < 16; ++q) {
            float4 v = er[q];
            e[q * 4 + 0] = v.x * inv; e[q * 4 + 1] = v.y * inv;
            e[q * 4 + 2] = v.z * inv; e[q * 4 + 3] = v.w * inv;
        }
        for (int l = 0; l < L; ++l) {
            float d = 0.f;
#pragma unroll
            for (int c = 0; c < 64; ++c) {
                float t = e[c] - cr[l * 64 + c];
                d += t * t;
            }
            float x = -sqrtf(d);
            out[1 + (size_t)row * L + l] = x;
            float y = labels[(size_t)row * L + l];
            lsum += fmaxf(x, 0.f) - x * y + log1pf(expf(-fabsf(x)));
        }
    }
#pragma unroll
    for (int off = 32; off > 0; off >>= 1) lsum += __shfl_down(lsum, off);
    __shared__ float red[4];
    if ((tid & 63) == 0) red[tid >> 6] = lsum;
    __syncthreads();
    if (tid == 0) atomicAdd(loss_acc, red[0] + red[1] + red[2] + red[3]);
}

__global__ void write_loss(const float* __restrict__ loss_acc,
                           float* __restrict__ out, float invBL)
{
    out[0] = loss_acc[0] * invBL;
}

// ---------------------------------------------------------------------------
extern "C" void kernel_launch(void* const* d_in, const int* in_sizes, int n_in,
                              void* d_out, int out_size, void* d_ws, size_t ws_size,
                              hipStream_t stream)
{
    const float* features    = (const float*)d_in[0];   // [B][D]
    const float* labels      = (const float*)d_in[1];   // [B][L]
    const float* g_weight    = (const float*)d_in[2];   // [F][D]
    const float* ex_features = (const float*)d_in[3];   // [N][D]
    const float* ex_reps     = (const float*)d_in[4];   // [N][C]
    const float* class_reps  = (const float*)d_in[5];   // [L][C]
    const int*   p_ptr       = (const int*)d_in[6];

    const int D = 1024;
    const int B = in_sizes[0] / D;          // 4096
    const int F = in_sizes[2] / D;          // 1024
    const int N = in_sizes[3] / D;          // 8192
    const int C = in_sizes[4] / N;          // 64
    const int L = in_sizes[5] / C;          // 28

    // workspace layout (round-5 proven)
    char* ws = (char*)d_ws;
    float*          Xf     = (float*)(ws);                            // B rows: fp32 then hi/lo in-place
    float*          Xe     = (float*)(ws + (size_t)B * 4096);         // N rows
    unsigned short* sp_w   = (unsigned short*)(ws + (size_t)(B + N) * 4096);           // F rows hi/lo
    unsigned short* exT    = (unsigned short*)(ws + (size_t)(B + N + F) * 4096);       // [64][N] bf16
    float*          echo   = (float*)(ws + (size_t)(B + N + F) * 4096 + (size_t)64 * N * 2);
    float*          rsums  = echo + (size_t)B * C;
    float*          loss_a = rsums + B;

    hipMemsetAsync(echo, 0, (size_t)(B * C + B + 4) * 4, stream);

    // prep: split W, transpose exR
    split_rows<<<F, 256, 0, stream>>>(g_weight, sp_w);
    transpose_exR<<<N / 256, 256, 0, stream>>>(ex_reps, exT, N);

    // projections: X @ W^T (bf16x3 MFMA, round-5 config)
    {
        dim3 g1(F / 128, B / 128);
        gemm_w<<<g1, 256, 0, stream>>>(features, sp_w, Xf, F, D);
        dim3 g2(F / 128, N / 128);
        gemm_w<<<g2, 256, 0, stream>>>(ex_features, sp_w, Xe, F, D);
    }

    // L2 normalize + split in-place
    l2norm_split<<<B, 256, 0, stream>>>(Xf);
    l2norm_split<<<N, 256, 0, stream>>>(Xe);

    // fused cosine^p + L1-fold + exemplar readout (128x256 tile, f32x4 accs)
    {
        dim3 g(B / 128, N / 512);
        fused_mfma5<<<g, 256, 0, stream>>>((const unsigned short*)Xf,
                                           (const unsigned short*)Xe,
                                           exT, echo, rsums, p_ptr, N, F);
    }

    // finalize: neg_dists + loss
    {
        dim3 g((B + 255) / 256);
        size_t shb = (size_t)L * C * sizeof(float);
        finalize_kernel<<<g, 256, shb, stream>>>(echo, rsums, class_reps, labels,
                                                 (float*)d_out, loss_a, B, L, C);
    }
    write_loss<<<1, 1, 0, stream>>>(loss_a, (float*)d_out, 1.f / (float)(B * L));
}